// Round 6
// baseline (171.751 us; speedup 1.0000x reference)
//
#include <hip/hip_runtime.h>
#include <cstdint>
#include <cstddef>

// 20-qubit statevector sim, 3 layers of [U3 x20 + CU3 ring (0,1)..(19,0)].
// 7 dispatches: 6 tile passes (2 per layer) + tiny mean-subtract kernel.
//
// R6 = R5 with the compile fix: __builtin_nontemporal_load/store requires
// scalar or ext_vector_type pointers (NOT HIP_vector_type float4/float2) --
// routed through nt4/nt2 ext_vector aliases, bit-identical layout.
//
// R5 rationale: evidence R0/R2/R3/R4 says pass internals and access
// patterns move total by <=5us; the constant is 7 dispatches x ~10us
// boundary (launch + per-XCD L2 writeback/invalidate). Inter-pass psi is
// written once, read once by the NEXT dispatch -> nontemporal stores
// bypass L2 (less dirty data to flush at each boundary), L3 (coherent
// point) still serves the reads. Applied to: pass input loads, inter-pass
// stores, final out stores, fin_k.
//
// Pass internals (R3): NT=512, v[4], 4 waves/SIMD, 512 blocks, 11-bit
// tiles; window = bits (0,1); rotate-by-1 per phase, 10 phases, 9
// rotations (double-buffered, XOR-bank-swizzle SW(i)=i^((i>>3)&1));
// U3+CU3 fused per phase (W0, W1 = u_c*U3 precomputed in LDS).
//
// Pass S1(k): U3 q0..q10 + CU3 (0,1)..(9,10); tile bits 0..10 = q0..q10,
//   block bits = q11..q19.  Phase p (window = tile bits (p,p+1)):
//   p=0: U0 standalone + F(U1,C01); p>=1: F(U_{p+1}, C_{p,p+1}).
// Pass S2(k): tile = (q10,q11..q19,q0), block = q1..q9.
//   p=0..8: F(U_{11+p}, C_{10+p,11+p}); p=9: raw C(19,0) (U3 q0 done in S1).
// After 9 rotations: regs j=(tile bit9, bit10), t = tile bits 0..8.
// Inter-pass store (R0/R3-verified): f4 = b + t0*2^9 + (t>>1)*2^10 +
//   j0*2^18, content pairs over j1; reader loads contiguous 32B/thread.
// Final readout: R = j0 + 2*rev9(t) + 1024*rev9(b) + 2^19*j1 ->
//   float2 (x0,x1) at f2 idx rev9(t)+512*rev9(b), (x2,x3) at +2^18.
//   Block sum -> atomicAdd(accum); fin_k subtracts mean.

#define NB 512
#define NT 512
#define SW(i) ((i) ^ (((i) >> 3) & 1u))

typedef float nt4 __attribute__((ext_vector_type(4)));
typedef float nt2 __attribute__((ext_vector_type(2)));

__device__ __forceinline__ float2 cmadd2(float2 m0, float2 a0, float2 m1, float2 a1) {
  float2 r;
  r.x = m0.x * a0.x - m0.y * a0.y + m1.x * a1.x - m1.y * a1.y;
  r.y = m0.x * a0.y + m0.y * a0.x + m1.x * a1.y + m1.y * a1.x;
  return r;
}
__device__ __forceinline__ float2 cmul(float2 a, float2 b) {
  return make_float2(a.x * b.x - a.y * b.y, a.x * b.y + a.y * b.x);
}
__device__ __forceinline__ float2 cadd(float2 a, float2 b) {
  return make_float2(a.x + b.x, a.y + b.y);
}

// U3 on window bit0: pairs (0,1),(2,3)
__device__ __forceinline__ void applyU3b0(float2* v, const float2* m) {
  float2 m00 = m[0], m01 = m[1], m10 = m[2], m11 = m[3];
  float2 a0 = v[0], a1 = v[1];
  v[0] = cmadd2(m00, a0, m01, a1); v[1] = cmadd2(m10, a0, m11, a1);
  a0 = v[2]; a1 = v[3];
  v[2] = cmadd2(m00, a0, m01, a1); v[3] = cmadd2(m10, a0, m11, a1);
}
// fused [U3 on bit1, then CU3(ctrl=bit0,tgt=bit1)]: W0 acts on (v0,v2), W1 on (v1,v3)
__device__ __forceinline__ void applyF(float2* v, const float2* W0, const float2* W1) {
  float2 a0 = v[0], a1 = v[2];
  v[0] = cmadd2(W0[0], a0, W0[1], a1); v[2] = cmadd2(W0[2], a0, W0[3], a1);
  a0 = v[1]; a1 = v[3];
  v[1] = cmadd2(W1[0], a0, W1[1], a1); v[3] = cmadd2(W1[2], a0, W1[3], a1);
}
// raw CU3 ctrl bit0, tgt bit1: only (v1,v3)
__device__ __forceinline__ void applyC(float2* v, const float2* u) {
  float2 a0 = v[1], a1 = v[3];
  v[1] = cmadd2(u[0], a0, u[1], a1); v[3] = cmadd2(u[2], a0, u[3], a1);
}

__device__ __forceinline__ float xval(float2 a) {
  float p = a.x * a.x + a.y * a.y;
  return powf(0.8f * tanhf(52428.8f * p), 0.3f);
}

__device__ __forceinline__ void mat_from(const float* s, float2* m) {
  float st, ct, sl, cl, sp, cp, spl, cpl;
  sincosf(0.5f * s[0], &st, &ct);
  sincosf(s[2], &sl, &cl);
  sincosf(s[1], &sp, &cp);
  sincosf(s[1] + s[2], &spl, &cpl);
  m[0] = make_float2(ct, 0.f);
  m[1] = make_float2(-cl * st, -sl * st);
  m[2] = make_float2(cp * st, sp * st);
  m[3] = make_float2(cpl * ct, spl * ct);
}

// TYPE 0 = S1, 1 = S2; INIT synthesizes |0..0>; FINAL does readout.
template <int TYPE, int INIT, int FINAL>
__global__ __launch_bounds__(NT, 4) void pass_k(const float* __restrict__ u3p,
                                                const float* __restrict__ cu3p, int k,
                                                const float2* __restrict__ in,
                                                float2* __restrict__ outPsi,
                                                float* __restrict__ accum,
                                                float* __restrict__ out) {
  __shared__ float4 A4[1024], B4[1024];  // rotation double-buffer (16 KB each)
  __shared__ float2 M[168];              // MU: U3 q at [4q]; MC=M+80: W1 link c at [4c]
  __shared__ float red[8];
  unsigned t = threadIdx.x, b = blockIdx.x;

  // start psi loads first so they overlap the sincos below
  float2 v[4];
  if (INIT) {
    v[0] = v[1] = v[2] = v[3] = make_float2(0.f, 0.f);
    if (b == 0 && t == 0) { v[0] = make_float2(1.f, 0.f); *accum = 0.f; }
  } else {
    const nt4* in4 = (const nt4*)in + ((size_t)b << 10) + 2u * t;
    nt4 f0 = __builtin_nontemporal_load(in4);
    nt4 f1 = __builtin_nontemporal_load(in4 + 1);
    v[0] = make_float2(f0.x, f0.y); v[1] = make_float2(f0.z, f0.w);
    v[2] = make_float2(f1.x, f1.y); v[3] = make_float2(f1.z, f1.w);
  }

  // this layer's matrices: MU[q] = U3(q); MC[c] = u_c * U3(c+1) (fused W1),
  // except MC[19] = raw u_19 (its target q0's U3 was already applied in S1).
  float2* MU = M;
  float2* MC = M + 80;
  if (t < 20) {
    mat_from(u3p + (k * 20 + t) * 3, MU + 4 * t);
  } else if (t >= 64 && t < 84) {
    unsigned c = t - 64;
    float2 u[4];
    mat_from(cu3p + (k * 20 + c) * 3, u);
    if (c == 19) {
      MC[76] = u[0]; MC[77] = u[1]; MC[78] = u[2]; MC[79] = u[3];
    } else {
      float2 ut[4];
      mat_from(u3p + (k * 20 + c + 1) * 3, ut);
      MC[4 * c + 0] = cadd(cmul(u[0], ut[0]), cmul(u[1], ut[2]));
      MC[4 * c + 1] = cadd(cmul(u[0], ut[1]), cmul(u[1], ut[3]));
      MC[4 * c + 2] = cadd(cmul(u[2], ut[0]), cmul(u[3], ut[2]));
      MC[4 * c + 3] = cadd(cmul(u[2], ut[1]), cmul(u[3], ut[3]));
    }
  }
  __syncthreads();

  // 10 phases; window = tile bits (p, p+1); rotate-by-1 between phases.
#pragma unroll
  for (int p = 0; p < 10; ++p) {
    if (TYPE == 0) {
      if (p == 0) applyU3b0(v, MU);             // U0 standalone
      applyF(v, MU + 4 * (p + 1), MC + 4 * p);  // U_{p+1} + C_{p,p+1}
    } else {
      if (p < 9) applyF(v, MU + 4 * (11 + p), MC + 4 * (10 + p));
      else       applyC(v, MC + 4 * 19);        // raw C(19,0)
    }
    if (p < 9) {
      // rotate-by-1: L' = (L>>1)|((L&1)<<10). Thread regs L=4t+j:
      // f4[t]=(v0,v2) [f2 2t,2t+1]; f4[t+512]=(v1,v3) [f2 2t+1024,+1025]
      float4* buf = (p & 1) ? B4 : A4;
      buf[SW(t)]        = make_float4(v[0].x, v[0].y, v[2].x, v[2].y);
      buf[SW(t + 512u)] = make_float4(v[1].x, v[1].y, v[3].x, v[3].y);
      __syncthreads();
      float4 fa = buf[SW(2u * t)], fb = buf[SW(2u * t + 1u)];
      v[0] = make_float2(fa.x, fa.y); v[1] = make_float2(fa.z, fa.w);
      v[2] = make_float2(fb.x, fb.y); v[3] = make_float2(fb.z, fb.w);
    }
  }

  // final regs: j=(tile bit9, bit10), t = tile bits 0..8.
  if (!FINAL) {
    // inter-pass layout: f4 = b + t0*2^9 + (t>>1)*2^10 + j0*2^18, pair over j1.
    nt4* o4 = (nt4*)outPsi;
    unsigned base = b + ((t & 1u) << 9) + ((t >> 1) << 10);
    nt4 s0 = {v[0].x, v[0].y, v[2].x, v[2].y};
    nt4 s1 = {v[1].x, v[1].y, v[3].x, v[3].y};
    __builtin_nontemporal_store(s0, o4 + base);
    __builtin_nontemporal_store(s1, o4 + base + (1u << 18));
  } else {
    // S2(2) end: j0=q19, j1=q0, t=(q10..q18), b=(q1..q9).
    // R = j0 + 2*rev9(t) + 1024*rev9(b) + 2^19*j1
    float xv0 = xval(v[0]), xv1 = xval(v[1]), xv2 = xval(v[2]), xv3 = xval(v[3]);
    float s = xv0 + xv1 + xv2 + xv3;
    nt2* o2 = (nt2*)out;
    unsigned rt = __brev(t) >> 23, rb = __brev(b) >> 23;
    unsigned base = rt + (rb << 9);
    nt2 s0 = {xv0, xv1};
    nt2 s1 = {xv2, xv3};
    __builtin_nontemporal_store(s0, o2 + base);
    __builtin_nontemporal_store(s1, o2 + base + (1u << 18));
#pragma unroll
    for (int o = 32; o > 0; o >>= 1) s += __shfl_down(s, o);
    if ((t & 63u) == 0) red[t >> 6] = s;
    __syncthreads();
    if (t == 0) {
      float tot = 0.f;
#pragma unroll
      for (int i = 0; i < 8; i++) tot += red[i];
      atomicAdd(accum, tot);
    }
  }
}

__global__ void fin_k(float* __restrict__ out, const float* __restrict__ accum) {
  unsigned i = blockIdx.x * blockDim.x + threadIdx.x;
  float mean = *accum * (1.f / 1048576.f);
  nt4* o4 = (nt4*)out;
  nt4 x = __builtin_nontemporal_load(o4 + i);
  x.x -= mean; x.y -= mean; x.z -= mean; x.w -= mean;
  __builtin_nontemporal_store(x, o4 + i);
}

extern "C" void kernel_launch(void* const* d_in, const int* in_sizes, int n_in,
                              void* d_out, int out_size, void* d_ws, size_t ws_size,
                              hipStream_t stream) {
  const float* u3p = (const float*)d_in[0];
  const float* cu3p = (const float*)d_in[1];
  float* out = (float*)d_out;

  char* ws = (char*)d_ws;
  float2* psiA = (float2*)ws;                              // 8 MB
  float2* psiB = (float2*)(ws + (size_t)8 * 1024 * 1024);  // 8 MB
  float* accum = (float*)(ws + (size_t)16 * 1024 * 1024);

  pass_k<0, 1, 0><<<NB, NT, 0, stream>>>(u3p, cu3p, 0, nullptr, psiB, accum, out);
  pass_k<1, 0, 0><<<NB, NT, 0, stream>>>(u3p, cu3p, 0, psiB, psiA, accum, out);
  pass_k<0, 0, 0><<<NB, NT, 0, stream>>>(u3p, cu3p, 1, psiA, psiB, accum, out);
  pass_k<1, 0, 0><<<NB, NT, 0, stream>>>(u3p, cu3p, 1, psiB, psiA, accum, out);
  pass_k<0, 0, 0><<<NB, NT, 0, stream>>>(u3p, cu3p, 2, psiA, psiB, accum, out);
  pass_k<1, 0, 1><<<NB, NT, 0, stream>>>(u3p, cu3p, 2, psiB, nullptr, accum, out);
  fin_k<<<1024, 256, 0, stream>>>(out, accum);
}

// Round 7
// 144.389 us; speedup vs baseline: 1.1895x; 1.1895x over previous
//
#include <hip/hip_runtime.h>
#include <cstdint>
#include <cstddef>

// 20-qubit statevector sim, 3 layers of [U3 x20 + CU3 ring (0,1)..(19,0)].
// R7 = R3 body (best measured: 135.4us) + 6 no-op PROBE dispatches
// interleaved between passes. Purpose: measure per-dispatch overhead
// directly as (dur - 135.4)/6 under the real timing path. R6 falsified
// the L2-writeback theory (nontemporal = +36us: L2 residency was helping,
// not hurting). Probes write only accum[8+i] (unused scratch) -> zero
// correctness risk.
//
// Pass internals (R3): NT=512, v[4], 4 waves/SIMD, 512 blocks, 11-bit
// tiles; window = bits (0,1); rotate-by-1 per phase, 10 phases, 9
// rotations (double-buffered, XOR-bank-swizzle SW(i)=i^((i>>3)&1));
// U3+CU3 fused per phase (W0, W1 = u_c*U3 precomputed in LDS).
//
// Pass S1(k): U3 q0..q10 + CU3 (0,1)..(9,10); tile bits 0..10 = q0..q10,
//   block bits = q11..q19.  Phase p (window = tile bits (p,p+1)):
//   p=0: U0 standalone + F(U1,C01); p>=1: F(U_{p+1}, C_{p,p+1}).
// Pass S2(k): tile = (q10,q11..q19,q0), block = q1..q9.
//   p=0..8: F(U_{11+p}, C_{10+p,11+p}); p=9: raw C(19,0) (U3 q0 done in S1).
// After 9 rotations: regs j=(tile bit9, bit10), t = tile bits 0..8.
// Inter-pass store (R0/R3-verified): f4 = b + t0*2^9 + (t>>1)*2^10 +
//   j0*2^18, content pairs over j1; reader loads contiguous 32B/thread.
// Final readout: R = j0 + 2*rev9(t) + 1024*rev9(b) + 2^19*j1 ->
//   float2 (x0,x1) at f2 idx rev9(t)+512*rev9(b), (x2,x3) at +2^18.
//   Block sum -> atomicAdd(accum); fin_k subtracts mean.

#define NB 512
#define NT 512
#define SW(i) ((i) ^ (((i) >> 3) & 1u))

__device__ __forceinline__ float2 cmadd2(float2 m0, float2 a0, float2 m1, float2 a1) {
  float2 r;
  r.x = m0.x * a0.x - m0.y * a0.y + m1.x * a1.x - m1.y * a1.y;
  r.y = m0.x * a0.y + m0.y * a0.x + m1.x * a1.y + m1.y * a1.x;
  return r;
}
__device__ __forceinline__ float2 cmul(float2 a, float2 b) {
  return make_float2(a.x * b.x - a.y * b.y, a.x * b.y + a.y * b.x);
}
__device__ __forceinline__ float2 cadd(float2 a, float2 b) {
  return make_float2(a.x + b.x, a.y + b.y);
}

// U3 on window bit0: pairs (0,1),(2,3)
__device__ __forceinline__ void applyU3b0(float2* v, const float2* m) {
  float2 m00 = m[0], m01 = m[1], m10 = m[2], m11 = m[3];
  float2 a0 = v[0], a1 = v[1];
  v[0] = cmadd2(m00, a0, m01, a1); v[1] = cmadd2(m10, a0, m11, a1);
  a0 = v[2]; a1 = v[3];
  v[2] = cmadd2(m00, a0, m01, a1); v[3] = cmadd2(m10, a0, m11, a1);
}
// fused [U3 on bit1, then CU3(ctrl=bit0,tgt=bit1)]: W0 acts on (v0,v2), W1 on (v1,v3)
__device__ __forceinline__ void applyF(float2* v, const float2* W0, const float2* W1) {
  float2 a0 = v[0], a1 = v[2];
  v[0] = cmadd2(W0[0], a0, W0[1], a1); v[2] = cmadd2(W0[2], a0, W0[3], a1);
  a0 = v[1]; a1 = v[3];
  v[1] = cmadd2(W1[0], a0, W1[1], a1); v[3] = cmadd2(W1[2], a0, W1[3], a1);
}
// raw CU3 ctrl bit0, tgt bit1: only (v1,v3)
__device__ __forceinline__ void applyC(float2* v, const float2* u) {
  float2 a0 = v[1], a1 = v[3];
  v[1] = cmadd2(u[0], a0, u[1], a1); v[3] = cmadd2(u[2], a0, u[3], a1);
}

__device__ __forceinline__ float xval(float2 a) {
  float p = a.x * a.x + a.y * a.y;
  return powf(0.8f * tanhf(52428.8f * p), 0.3f);
}

__device__ __forceinline__ void mat_from(const float* s, float2* m) {
  float st, ct, sl, cl, sp, cp, spl, cpl;
  sincosf(0.5f * s[0], &st, &ct);
  sincosf(s[2], &sl, &cl);
  sincosf(s[1], &sp, &cp);
  sincosf(s[1] + s[2], &spl, &cpl);
  m[0] = make_float2(ct, 0.f);
  m[1] = make_float2(-cl * st, -sl * st);
  m[2] = make_float2(cp * st, sp * st);
  m[3] = make_float2(cpl * ct, spl * ct);
}

// TYPE 0 = S1, 1 = S2; INIT synthesizes |0..0>; FINAL does readout.
template <int TYPE, int INIT, int FINAL>
__global__ __launch_bounds__(NT, 4) void pass_k(const float* __restrict__ u3p,
                                                const float* __restrict__ cu3p, int k,
                                                const float2* __restrict__ in,
                                                float2* __restrict__ outPsi,
                                                float* __restrict__ accum,
                                                float* __restrict__ out) {
  __shared__ float4 A4[1024], B4[1024];  // rotation double-buffer (16 KB each)
  __shared__ float2 M[168];              // MU: U3 q at [4q]; MC=M+80: W1 link c at [4c]
  __shared__ float red[8];
  unsigned t = threadIdx.x, b = blockIdx.x;

  // start psi loads first so they overlap the sincos below
  float2 v[4];
  if (INIT) {
    v[0] = v[1] = v[2] = v[3] = make_float2(0.f, 0.f);
    if (b == 0 && t == 0) { v[0] = make_float2(1.f, 0.f); *accum = 0.f; }
  } else {
    const float4* in4 = (const float4*)in + ((size_t)b << 10) + 2u * t;
    float4 f0 = in4[0], f1 = in4[1];
    v[0] = make_float2(f0.x, f0.y); v[1] = make_float2(f0.z, f0.w);
    v[2] = make_float2(f1.x, f1.y); v[3] = make_float2(f1.z, f1.w);
  }

  // this layer's matrices: MU[q] = U3(q); MC[c] = u_c * U3(c+1) (fused W1),
  // except MC[19] = raw u_19 (its target q0's U3 was already applied in S1).
  float2* MU = M;
  float2* MC = M + 80;
  if (t < 20) {
    mat_from(u3p + (k * 20 + t) * 3, MU + 4 * t);
  } else if (t >= 64 && t < 84) {
    unsigned c = t - 64;
    float2 u[4];
    mat_from(cu3p + (k * 20 + c) * 3, u);
    if (c == 19) {
      MC[76] = u[0]; MC[77] = u[1]; MC[78] = u[2]; MC[79] = u[3];
    } else {
      float2 ut[4];
      mat_from(u3p + (k * 20 + c + 1) * 3, ut);
      MC[4 * c + 0] = cadd(cmul(u[0], ut[0]), cmul(u[1], ut[2]));
      MC[4 * c + 1] = cadd(cmul(u[0], ut[1]), cmul(u[1], ut[3]));
      MC[4 * c + 2] = cadd(cmul(u[2], ut[0]), cmul(u[3], ut[2]));
      MC[4 * c + 3] = cadd(cmul(u[2], ut[1]), cmul(u[3], ut[3]));
    }
  }
  __syncthreads();

  // 10 phases; window = tile bits (p, p+1); rotate-by-1 between phases.
#pragma unroll
  for (int p = 0; p < 10; ++p) {
    if (TYPE == 0) {
      if (p == 0) applyU3b0(v, MU);             // U0 standalone
      applyF(v, MU + 4 * (p + 1), MC + 4 * p);  // U_{p+1} + C_{p,p+1}
    } else {
      if (p < 9) applyF(v, MU + 4 * (11 + p), MC + 4 * (10 + p));
      else       applyC(v, MC + 4 * 19);        // raw C(19,0)
    }
    if (p < 9) {
      // rotate-by-1: L' = (L>>1)|((L&1)<<10). Thread regs L=4t+j:
      // f4[t]=(v0,v2) [f2 2t,2t+1]; f4[t+512]=(v1,v3) [f2 2t+1024,+1025]
      float4* buf = (p & 1) ? B4 : A4;
      buf[SW(t)]        = make_float4(v[0].x, v[0].y, v[2].x, v[2].y);
      buf[SW(t + 512u)] = make_float4(v[1].x, v[1].y, v[3].x, v[3].y);
      __syncthreads();
      float4 fa = buf[SW(2u * t)], fb = buf[SW(2u * t + 1u)];
      v[0] = make_float2(fa.x, fa.y); v[1] = make_float2(fa.z, fa.w);
      v[2] = make_float2(fb.x, fb.y); v[3] = make_float2(fb.z, fb.w);
    }
  }

  // final regs: j=(tile bit9, bit10), t = tile bits 0..8.
  if (!FINAL) {
    // inter-pass layout: f4 = b + t0*2^9 + (t>>1)*2^10 + j0*2^18, pair over j1.
    float4* o4 = (float4*)outPsi;
    unsigned base = b + ((t & 1u) << 9) + ((t >> 1) << 10);
    o4[base]              = make_float4(v[0].x, v[0].y, v[2].x, v[2].y);
    o4[base + (1u << 18)] = make_float4(v[1].x, v[1].y, v[3].x, v[3].y);
  } else {
    // S2(2) end: j0=q19, j1=q0, t=(q10..q18), b=(q1..q9).
    // R = j0 + 2*rev9(t) + 1024*rev9(b) + 2^19*j1
    float xv0 = xval(v[0]), xv1 = xval(v[1]), xv2 = xval(v[2]), xv3 = xval(v[3]);
    float s = xv0 + xv1 + xv2 + xv3;
    float2* o2 = (float2*)out;
    unsigned rt = __brev(t) >> 23, rb = __brev(b) >> 23;
    unsigned base = rt + (rb << 9);
    o2[base] = make_float2(xv0, xv1);
    o2[base + (1u << 18)] = make_float2(xv2, xv3);
#pragma unroll
    for (int o = 32; o > 0; o >>= 1) s += __shfl_down(s, o);
    if ((t & 63u) == 0) red[t >> 6] = s;
    __syncthreads();
    if (t == 0) {
      float tot = 0.f;
#pragma unroll
      for (int i = 0; i < 8; i++) tot += red[i];
      atomicAdd(accum, tot);
    }
  }
}

// no-op probe: measures pure per-dispatch overhead. Writes only unused
// scratch (accum[8+tag]) so the compiler/runtime can't elide it.
__global__ void probe_k(float* __restrict__ accum, int tag) {
  if (threadIdx.x == 0) accum[8 + tag] = (float)tag;
}

__global__ void fin_k(float* __restrict__ out, const float* __restrict__ accum) {
  unsigned i = blockIdx.x * blockDim.x + threadIdx.x;
  float mean = *accum * (1.f / 1048576.f);
  float4* o4 = (float4*)out;
  float4 x = o4[i];
  x.x -= mean; x.y -= mean; x.z -= mean; x.w -= mean;
  o4[i] = x;
}

extern "C" void kernel_launch(void* const* d_in, const int* in_sizes, int n_in,
                              void* d_out, int out_size, void* d_ws, size_t ws_size,
                              hipStream_t stream) {
  const float* u3p = (const float*)d_in[0];
  const float* cu3p = (const float*)d_in[1];
  float* out = (float*)d_out;

  char* ws = (char*)d_ws;
  float2* psiA = (float2*)ws;                              // 8 MB
  float2* psiB = (float2*)(ws + (size_t)8 * 1024 * 1024);  // 8 MB
  float* accum = (float*)(ws + (size_t)16 * 1024 * 1024);  // [0]=sum, [8..13]=probe scratch

  pass_k<0, 1, 0><<<NB, NT, 0, stream>>>(u3p, cu3p, 0, nullptr, psiB, accum, out);
  probe_k<<<1, 64, 0, stream>>>(accum, 0);
  pass_k<1, 0, 0><<<NB, NT, 0, stream>>>(u3p, cu3p, 0, psiB, psiA, accum, out);
  probe_k<<<1, 64, 0, stream>>>(accum, 1);
  pass_k<0, 0, 0><<<NB, NT, 0, stream>>>(u3p, cu3p, 1, psiA, psiB, accum, out);
  probe_k<<<1, 64, 0, stream>>>(accum, 2);
  pass_k<1, 0, 0><<<NB, NT, 0, stream>>>(u3p, cu3p, 1, psiB, psiA, accum, out);
  probe_k<<<1, 64, 0, stream>>>(accum, 3);
  pass_k<0, 0, 0><<<NB, NT, 0, stream>>>(u3p, cu3p, 2, psiA, psiB, accum, out);
  probe_k<<<1, 64, 0, stream>>>(accum, 4);
  pass_k<1, 0, 1><<<NB, NT, 0, stream>>>(u3p, cu3p, 2, psiB, nullptr, accum, out);
  probe_k<<<1, 64, 0, stream>>>(accum, 5);
  fin_k<<<1024, 256, 0, stream>>>(out, accum);
}

// Round 8
// 138.952 us; speedup vs baseline: 1.2360x; 1.0391x over previous
//
#include <hip/hip_runtime.h>
#include <cstdint>
#include <cstddef>

// 20-qubit statevector sim, 3 layers of [U3 x20 + CU3 ring (0,1)..(19,0)].
// 7 dispatches: 6 tile passes (2 per layer) + tiny mean-subtract kernel.
//
// R8: 12-bit tiles + single-block cache-line ownership for ALL inter-pass
// I/O. R7 probe measured dispatch overhead = 1.5us/dispatch -> ~123us is
// IN the passes; model gap traced to the inter-pass scatter: old layout
// put block bits in the low address bits, so every 64B line was written
// 16B-each by 4 different blocks on 4 different XCDs (non-coherent L2s
// can't merge -> partial-line RMW at L3, ~4x amplification; R4's read-side
// variant had the mirror cost). Requirement: every line fully produced AND
// consumed by ONE block. Tile-set intersection must be >= line size:
// 11-bit tiles give 2 shared bits (32B) — impossible; 12-bit tiles give
// {q0,q9,q10,q11} = 4 shared bits = 128B. ✓
//
// Structure: 256 blocks x 1024 threads (1 block/CU, 16 waves, 4/SIMD),
// v[4], window = local bits (0,1), rotate-by-1 via LDS double-buffer
// (XOR-swizzle SW), U3+CU3 fused per phase (W0, W1=u_c*U3 in LDS).
// S1(k): local {q0..q11}: U3 q0..q11 + links (0,1)..(10,11):
//   11 phases (p=0: +U0 standalone), 10 rotations. Final regs (q10,q11),
//   t[0..9]=q0..q9, block b = q12..q19.
// S2(k): local {q9..q19,q0}, window order q11,q12,..,q19,q0,(q9,q10):
//   9 phases (p=0..7: F(U_{12+p}, C_{11+p,12+p}); p=8: raw C(19,0)),
//   8 rotations, +1 extra rotation if non-final -> regs (q0,q9),
//   t[0..9]=(q10,q11,q12..q19), block = q1..q8.
// Buffer P (S1->S2), f2 addr bits: [q11,q10,q0,q9 | q1..q8 | q12..q19].
//   S1 writes 32B/thread, 2KB/wave contiguous; S2 reads 2x16B/thread,
//   lines assembled 128B single-block. Spot-verified: q0,q5,q9,q10,q11,
//   q12,q19 round-trips.
// Buffer B (S2->S1), f2 addr bits: [q0,q9,q10,q11 | q12..q19 | q1..q8].
//   S2 writes 32B/thread fully streaming; S1 reads 2x16B/thread, 128B
//   single-block lines. Spot-verified: q0,q1,q9,q10,q12,q13.
// FINAL (S2(2), no extra rot): regs (q19,q0), t=(q9,q10,q11..q18),
//   b=(q1..q8). R = sum q_i*2^(19-i) -> f2 idx = rev8((t>>2)&255)
//   + t[1]*256 + t[0]*512 + rev8(b)*1024 + j1*2^18, pair over j0=q19.
//   Spot-verified: q19,q0,q10,q1,q11. Block sum -> atomicAdd(accum);
//   fin_k subtracts mean.

#define NB 256
#define NT 1024
#define SW(i) ((i) ^ (((i) >> 3) & 1u))

__device__ __forceinline__ float2 cmadd2(float2 m0, float2 a0, float2 m1, float2 a1) {
  float2 r;
  r.x = m0.x * a0.x - m0.y * a0.y + m1.x * a1.x - m1.y * a1.y;
  r.y = m0.x * a0.y + m0.y * a0.x + m1.x * a1.y + m1.y * a1.x;
  return r;
}
__device__ __forceinline__ float2 cmul(float2 a, float2 b) {
  return make_float2(a.x * b.x - a.y * b.y, a.x * b.y + a.y * b.x);
}
__device__ __forceinline__ float2 cadd(float2 a, float2 b) {
  return make_float2(a.x + b.x, a.y + b.y);
}

// U3 on window bit0: pairs (0,1),(2,3)
__device__ __forceinline__ void applyU3b0(float2* v, const float2* m) {
  float2 m00 = m[0], m01 = m[1], m10 = m[2], m11 = m[3];
  float2 a0 = v[0], a1 = v[1];
  v[0] = cmadd2(m00, a0, m01, a1); v[1] = cmadd2(m10, a0, m11, a1);
  a0 = v[2]; a1 = v[3];
  v[2] = cmadd2(m00, a0, m01, a1); v[3] = cmadd2(m10, a0, m11, a1);
}
// fused [U3 on bit1, then CU3(ctrl=bit0,tgt=bit1)]: W0 acts on (v0,v2), W1 on (v1,v3)
__device__ __forceinline__ void applyF(float2* v, const float2* W0, const float2* W1) {
  float2 a0 = v[0], a1 = v[2];
  v[0] = cmadd2(W0[0], a0, W0[1], a1); v[2] = cmadd2(W0[2], a0, W0[3], a1);
  a0 = v[1]; a1 = v[3];
  v[1] = cmadd2(W1[0], a0, W1[1], a1); v[3] = cmadd2(W1[2], a0, W1[3], a1);
}
// raw CU3 ctrl bit0, tgt bit1: only (v1,v3)
__device__ __forceinline__ void applyC(float2* v, const float2* u) {
  float2 a0 = v[1], a1 = v[3];
  v[1] = cmadd2(u[0], a0, u[1], a1); v[3] = cmadd2(u[2], a0, u[3], a1);
}

__device__ __forceinline__ float xval(float2 a) {
  float p = a.x * a.x + a.y * a.y;
  return powf(0.8f * tanhf(52428.8f * p), 0.3f);
}

__device__ __forceinline__ void mat_from(const float* s, float2* m) {
  float st, ct, sl, cl, sp, cp, spl, cpl;
  sincosf(0.5f * s[0], &st, &ct);
  sincosf(s[2], &sl, &cl);
  sincosf(s[1], &sp, &cp);
  sincosf(s[1] + s[2], &spl, &cpl);
  m[0] = make_float2(ct, 0.f);
  m[1] = make_float2(-cl * st, -sl * st);
  m[2] = make_float2(cp * st, sp * st);
  m[3] = make_float2(cpl * ct, spl * ct);
}

// TYPE 0 = S1, 1 = S2; INIT synthesizes |0..0>; FINAL does readout.
template <int TYPE, int INIT, int FINAL>
__global__ __launch_bounds__(NT, 4) void pass_k(const float* __restrict__ u3p,
                                                const float* __restrict__ cu3p, int k,
                                                const float2* __restrict__ in,
                                                float2* __restrict__ outPsi,
                                                float* __restrict__ accum,
                                                float* __restrict__ out) {
  __shared__ float4 A4[2700], B4[2700];  // rotation dbuf; 86.4KB -> 1 block/CU
  __shared__ float2 M[168];              // MU: U3 q at [4q]; MC=M+80: W1 link c at [4c]
  __shared__ float red[16];
  unsigned t = threadIdx.x, b = blockIdx.x;

  // start psi loads first so they overlap the sincos below
  float2 v[4];
  if (INIT) {
    v[0] = v[1] = v[2] = v[3] = make_float2(0.f, 0.f);
    if (b == 0 && t == 0) { v[0] = make_float2(1.f, 0.f); *accum = 0.f; }
  } else {
    const float4* in4 = (const float4*)in;
    unsigned F;
    if (TYPE == 0)  // S1 reader of layout B: regs (q0,q1); t=(q2..q11)
      F = ((t >> 7) & 1u) + 2u * ((t >> 8) & 1u) + 4u * ((t >> 9) & 1u) +
          (b << 3) + ((t & 127u) << 12);
    else            // S2 reader of layout P: regs (q11,q12); t=(q13..q19,q0,q9,q10)
      F = ((t >> 9) & 1u) + 2u * ((t >> 7) & 1u) + 4u * ((t >> 8) & 1u) +
          (b << 3) + ((t & 127u) << 12);
    float4 f0 = in4[F], f1 = in4[F + 2048u];
    v[0] = make_float2(f0.x, f0.y); v[1] = make_float2(f0.z, f0.w);
    v[2] = make_float2(f1.x, f1.y); v[3] = make_float2(f1.z, f1.w);
  }

  // this layer's matrices: MU[q] = U3(q); MC[c] = u_c * U3(c+1) (fused W1),
  // except MC[19] = raw u_19 (its target q0's U3 was applied in S1).
  float2* MU = M;
  float2* MC = M + 80;
  if (t < 20) {
    mat_from(u3p + (k * 20 + t) * 3, MU + 4 * t);
  } else if (t >= 64 && t < 84) {
    unsigned c = t - 64;
    float2 u[4];
    mat_from(cu3p + (k * 20 + c) * 3, u);
    if (c == 19) {
      MC[76] = u[0]; MC[77] = u[1]; MC[78] = u[2]; MC[79] = u[3];
    } else {
      float2 ut[4];
      mat_from(u3p + (k * 20 + c + 1) * 3, ut);
      MC[4 * c + 0] = cadd(cmul(u[0], ut[0]), cmul(u[1], ut[2]));
      MC[4 * c + 1] = cadd(cmul(u[0], ut[1]), cmul(u[1], ut[3]));
      MC[4 * c + 2] = cadd(cmul(u[2], ut[0]), cmul(u[3], ut[2]));
      MC[4 * c + 3] = cadd(cmul(u[2], ut[1]), cmul(u[3], ut[3]));
    }
  }
  __syncthreads();

  // phases; window = local bits (0,1); rotate-by-1 between phases.
  constexpr int NP = TYPE ? 9 : 11;
#pragma unroll
  for (int p = 0; p < NP; ++p) {
    if (TYPE == 0) {
      if (p == 0) applyU3b0(v, MU);               // U0 standalone
      applyF(v, MU + 4 * (p + 1), MC + 4 * p);    // U_{p+1} + C_{p,p+1}
    } else {
      if (p < 8) applyF(v, MU + 4 * (12 + p), MC + 4 * (11 + p));
      else       applyC(v, MC + 4 * 19);          // raw C(19,0)
    }
    if (p < NP - 1 || (TYPE == 1 && !FINAL)) {
      // rotate-by-1: L' = (L>>1)|((L&1)<<11). Regs L=4t+j:
      // f4[t]=(v0,v2); f4[t+1024]=(v1,v3); reload f4[2t],f4[2t+1].
      float4* buf = (p & 1) ? B4 : A4;
      buf[SW(t)]         = make_float4(v[0].x, v[0].y, v[2].x, v[2].y);
      buf[SW(t + 1024u)] = make_float4(v[1].x, v[1].y, v[3].x, v[3].y);
      __syncthreads();
      float4 fa = buf[SW(2u * t)], fb = buf[SW(2u * t + 1u)];
      v[0] = make_float2(fa.x, fa.y); v[1] = make_float2(fa.z, fa.w);
      v[2] = make_float2(fb.x, fb.y); v[3] = make_float2(fb.z, fb.w);
    }
  }

  if (!FINAL) {
    float4* o4 = (float4*)outPsi;
    if (TYPE == 0) {
      // S1 end: regs j=(q10,q11), t=(q0..q9). Layout P:
      // A = q11 + 2q10 + 4q0 + 8q9 + (q1..q8)<<4 + (q12..q19)<<12
      unsigned F = 2u * (t & 1u) + 4u * ((t >> 9) & 1u) +
                   (((t >> 1) & 255u) << 3) + (b << 11);
      o4[F]      = make_float4(v[0].x, v[0].y, v[2].x, v[2].y);
      o4[F + 1u] = make_float4(v[1].x, v[1].y, v[3].x, v[3].y);
    } else {
      // S2 end (+extra rot): regs j=(q0,q9), t=(q10,q11,q12..q19). Layout B:
      // A = q0 + 2q9 + 4q10 + 8q11 + (q12..q19)<<4 + (q1..q8)<<12
      unsigned F = (t << 1) + (b << 11);
      o4[F]      = make_float4(v[0].x, v[0].y, v[1].x, v[1].y);
      o4[F + 1u] = make_float4(v[2].x, v[2].y, v[3].x, v[3].y);
    }
  } else {
    // S2(2) end (no extra rot): j0=q19, j1=q0, t=(q9,q10,q11..q18), b=(q1..q8).
    // R = j0 + 2*idx; idx = rev8((t>>2)&255) + t1*256 + t0*512 + rev8(b)*1024 + j1*2^18
    float xv0 = xval(v[0]), xv1 = xval(v[1]), xv2 = xval(v[2]), xv3 = xval(v[3]);
    float s = xv0 + xv1 + xv2 + xv3;
    float2* o2 = (float2*)out;
    unsigned rt8 = __brev((t >> 2) & 255u) >> 24;
    unsigned rb8 = __brev(b & 255u) >> 24;
    unsigned idx = rt8 + (((t >> 1) & 1u) << 8) + ((t & 1u) << 9) + (rb8 << 10);
    o2[idx]              = make_float2(xv0, xv1);
    o2[idx + (1u << 18)] = make_float2(xv2, xv3);
#pragma unroll
    for (int o = 32; o > 0; o >>= 1) s += __shfl_down(s, o);
    if ((t & 63u) == 0) red[t >> 6] = s;
    __syncthreads();
    if (t == 0) {
      float tot = 0.f;
#pragma unroll
      for (int i = 0; i < 16; i++) tot += red[i];
      atomicAdd(accum, tot);
    }
  }
}

__global__ void fin_k(float* __restrict__ out, const float* __restrict__ accum) {
  unsigned i = blockIdx.x * blockDim.x + threadIdx.x;
  float mean = *accum * (1.f / 1048576.f);
  float4* o4 = (float4*)out;
  float4 x = o4[i];
  x.x -= mean; x.y -= mean; x.z -= mean; x.w -= mean;
  o4[i] = x;
}

extern "C" void kernel_launch(void* const* d_in, const int* in_sizes, int n_in,
                              void* d_out, int out_size, void* d_ws, size_t ws_size,
                              hipStream_t stream) {
  const float* u3p = (const float*)d_in[0];
  const float* cu3p = (const float*)d_in[1];
  float* out = (float*)d_out;

  char* ws = (char*)d_ws;
  float2* psiA = (float2*)ws;                              // 8 MB
  float2* psiB = (float2*)(ws + (size_t)8 * 1024 * 1024);  // 8 MB
  float* accum = (float*)(ws + (size_t)16 * 1024 * 1024);

  pass_k<0, 1, 0><<<NB, NT, 0, stream>>>(u3p, cu3p, 0, nullptr, psiB, accum, out);
  pass_k<1, 0, 0><<<NB, NT, 0, stream>>>(u3p, cu3p, 0, psiB, psiA, accum, out);
  pass_k<0, 0, 0><<<NB, NT, 0, stream>>>(u3p, cu3p, 1, psiA, psiB, accum, out);
  pass_k<1, 0, 0><<<NB, NT, 0, stream>>>(u3p, cu3p, 1, psiB, psiA, accum, out);
  pass_k<0, 0, 0><<<NB, NT, 0, stream>>>(u3p, cu3p, 2, psiA, psiB, accum, out);
  pass_k<1, 0, 1><<<NB, NT, 0, stream>>>(u3p, cu3p, 2, psiB, nullptr, accum, out);
  fin_k<<<1024, 256, 0, stream>>>(out, accum);
}